// Round 3
// baseline (561.547 us; speedup 1.0000x reference)
//
#include <hip/hip_runtime.h>

#define NVOX 400000
#define K27 27
#define EPS_ 1e-5f

typedef __attribute__((ext_vector_type(8))) short short8;
typedef __attribute__((ext_vector_type(4))) float floatx4;
typedef __attribute__((ext_vector_type(4))) unsigned int uintx4;

// round-to-nearest-even fp32 -> bf16, packed pair (a low 16, b high 16)
__device__ __forceinline__ unsigned int pack2bf(float a, float b) {
    unsigned int ua = __builtin_bit_cast(unsigned int, a);
    unsigned int ub = __builtin_bit_cast(unsigned int, b);
    ua += 0x7fffu + ((ua >> 16) & 1u);
    ub += 0x7fffu + ((ub >> 16) & 1u);
    return (ua >> 16) | (ub & 0xffff0000u);
}

// blocks [0, feat_blocks): fp32->bf16 feature conversion (8 elems/thread)
// blocks [feat_blocks, feat_blocks+2): W[k][ci][co] -> wt[k][co][ci] bf16
// block  [feat_blocks+2]: zero the 128 stats accumulators
__global__ void prep_kernel(const float* __restrict__ w,
                            const float* __restrict__ feat,
                            unsigned short* __restrict__ feat_bf,
                            unsigned short* __restrict__ wt,
                            float* __restrict__ sums,
                            int feat_blocks) {
    const int b = blockIdx.x;
    const int t = threadIdx.x;
    if (b < feat_blocks) {
        const int i0 = b * 2048 + t * 8;
        const floatx4* s = (const floatx4*)(feat + i0);
        const floatx4 f0 = s[0], f1 = s[1];
        uintx4 v;
        v[0] = pack2bf(f0[0], f0[1]); v[1] = pack2bf(f0[2], f0[3]);
        v[2] = pack2bf(f1[0], f1[1]); v[3] = pack2bf(f1[2], f1[3]);
        *(uintx4*)(feat_bf + i0) = v;
    } else if (b < feat_blocks + 2) {
        const int g0 = (b - feat_blocks) * 256 + t;
        for (int g = g0; g < K27 * 64 * 64; g += 512) {
            const int k = g >> 12, r = g & 4095, co = r >> 6, ci = r & 63;
            unsigned int u =
                __builtin_bit_cast(unsigned int, w[(k << 12) + (ci << 6) + co]);
            u += 0x7fffu + ((u >> 16) & 1u);
            wt[g] = (unsigned short)(u >> 16);
        }
    } else {
        if (t < 128) sums[t] = 0.0f;
    }
}

// LDS-free, barrier-free conv: 256 rows x 64 out-ch per block, 4 waves, each
// wave M=64 x N=64 via 4x4 tiles of mfma_f32_16x16x32_bf16. Fragments are
// loaded DIRECTLY from global into registers:
//   A: lane(m,q) frag = feat_bf[nmap[k][row]][kb*32 + q*8 ..+8]  (16B load,
//      exec-masked on idx<0 -> zero frag; register contents byte-identical
//      to R1's verified LDS path)
//   B: lane(m,q) frag = wt[k][nt*16+m][kb*32 + q*8 ..+8]        (L1/L2-hot)
// Per-channel sum/sumsq fused into the epilogue.
template <bool BF16FEAT>
__launch_bounds__(256)
__global__ void conv_mfma(const float* __restrict__ feat,
                          const unsigned short* __restrict__ feat_bf,
                          const int* __restrict__ nmap,
                          const unsigned short* __restrict__ wt,
                          float* __restrict__ out,
                          float* __restrict__ sums) {
    __shared__ float cstat[128];

    const int tid  = threadIdx.x;
    const int wv   = tid >> 6;
    const int lane = tid & 63;
    const int m    = lane & 15;
    const int q    = lane >> 4;
    const int base = blockIdx.x * 256 + wv * 64;

    int rows[4];
#pragma unroll
    for (int mt = 0; mt < 4; ++mt) rows[mt] = base + mt * 16 + m;

    floatx4 acc[4][4];
#pragma unroll
    for (int mt = 0; mt < 4; ++mt)
#pragma unroll
        for (int nt = 0; nt < 4; ++nt)
            acc[mt][nt] = (floatx4){0.f, 0.f, 0.f, 0.f};

    for (int k = 0; k < K27; ++k) {
        int idx[4];
#pragma unroll
        for (int mt = 0; mt < 4; ++mt)
            idx[mt] = (rows[mt] < NVOX) ? nmap[k * NVOX + rows[mt]] : -1;

#pragma unroll
        for (int kb = 0; kb < 2; ++kb) {
            const int koff = kb * 32 + q * 8;
            short8 af[4];
#pragma unroll
            for (int mt = 0; mt < 4; ++mt) {
                af[mt] = (short8){0, 0, 0, 0, 0, 0, 0, 0};
                if (idx[mt] >= 0) {
                    if (BF16FEAT) {
                        af[mt] = *(const short8*)(feat_bf +
                                                  (size_t)idx[mt] * 64 + koff);
                    } else {
                        const floatx4* s =
                            (const floatx4*)(feat + (size_t)idx[mt] * 64 + koff);
                        const floatx4 f0 = s[0], f1 = s[1];
                        uintx4 v;
                        v[0] = pack2bf(f0[0], f0[1]); v[1] = pack2bf(f0[2], f0[3]);
                        v[2] = pack2bf(f1[0], f1[1]); v[3] = pack2bf(f1[2], f1[3]);
                        af[mt] = __builtin_bit_cast(short8, v);
                    }
                }
            }
            short8 bf[4];
#pragma unroll
            for (int nt = 0; nt < 4; ++nt)
                bf[nt] = *(const short8*)(wt + ((k * 64 + nt * 16 + m) << 6) + koff);
#pragma unroll
            for (int mt = 0; mt < 4; ++mt)
#pragma unroll
                for (int nt = 0; nt < 4; ++nt)
                    acc[mt][nt] = __builtin_amdgcn_mfma_f32_16x16x32_bf16(
                        af[mt], bf[nt], acc[mt][nt], 0, 0, 0);
        }
    }

    // epilogue: store (C/D: col=lane&15, row=q*4+reg — m89-verified) + stats
    if (tid < 128) cstat[tid] = 0.0f;
    __syncthreads();
#pragma unroll
    for (int nt = 0; nt < 4; ++nt) {
        const int col = nt * 16 + m;
        float s = 0.f, s2 = 0.f;
#pragma unroll
        for (int mt = 0; mt < 4; ++mt) {
            const int row0 = base + mt * 16 + q * 4;
#pragma unroll
            for (int i = 0; i < 4; ++i) {
                const float v = acc[mt][nt][i];
                s += v;
                s2 += v * v;
                if (row0 + i < NVOX) out[(size_t)(row0 + i) * 64 + col] = v;
            }
        }
        atomicAdd(&cstat[col], s);
        atomicAdd(&cstat[64 + col], s2);
    }
    __syncthreads();
    if (tid < 128) atomicAdd(&sums[tid], cstat[tid]);
}

__global__ void bn_apply(float* __restrict__ out, const float* __restrict__ sums,
                         const float* __restrict__ gamma,
                         const float* __restrict__ beta) {
    __shared__ float sc[64];
    __shared__ float sh[64];
    const int tid = threadIdx.x;
    if (tid < 64) {
        const float inv_n = 1.0f / (float)NVOX;
        const float mean = sums[tid] * inv_n;
        const float var  = sums[64 + tid] * inv_n - mean * mean;
        const float g    = gamma[tid] * rsqrtf(var + EPS_);
        sc[tid] = g;
        sh[tid] = beta[tid] - mean * g;
    }
    __syncthreads();
    const int cg = (tid & 15) * 4;
    floatx4 scale, shift;
#pragma unroll
    for (int j = 0; j < 4; ++j) {
        scale[j] = sc[cg + j];
        shift[j] = sh[cg + j];
    }
    floatx4* p = (floatx4*)out;
    const int total4 = NVOX * 16;
    for (int i = blockIdx.x * 256 + tid; i < total4; i += gridDim.x * 256) {
        floatx4 v = p[i] * scale + shift;
#pragma unroll
        for (int j = 0; j < 4; ++j) v[j] = v[j] > 0.f ? v[j] : 0.f;
        p[i] = v;
    }
}

extern "C" void kernel_launch(void* const* d_in, const int* in_sizes, int n_in,
                              void* d_out, int out_size, void* d_ws, size_t ws_size,
                              hipStream_t stream) {
    const float* feat  = (const float*)d_in[0];
    const int*   nmap  = (const int*)d_in[1];
    const float* w     = (const float*)d_in[2];
    const float* gamma = (const float*)d_in[3];
    const float* beta  = (const float*)d_in[4];
    float* out = (float*)d_out;

    const size_t FEATB = (size_t)NVOX * 64 * 2;      // 51,200,000
    const size_t WTB   = (size_t)K27 * 64 * 64 * 2;  //    221,184
    const int conv_blocks = (NVOX + 255) / 256;      // 1563

    if (ws_size >= FEATB + WTB + 512) {
        unsigned short* feat_bf = (unsigned short*)d_ws;
        unsigned short* wt      = (unsigned short*)((char*)d_ws + FEATB);
        float* sums             = (float*)((char*)d_ws + FEATB + WTB);
        prep_kernel<<<dim3(12503), dim3(256), 0, stream>>>(
            w, feat, feat_bf, wt, sums, 12500);
        conv_mfma<true><<<dim3(conv_blocks), dim3(256), 0, stream>>>(
            feat, feat_bf, nmap, wt, out, sums);
        bn_apply<<<dim3(2048), dim3(256), 0, stream>>>(out, sums, gamma, beta);
    } else {
        // fallback: fp32 gather + in-register pack (no feature buffer)
        unsigned short* wt = (unsigned short*)d_ws;
        float* sums        = (float*)((char*)d_ws + WTB);
        prep_kernel<<<dim3(3), dim3(256), 0, stream>>>(
            w, feat, nullptr, wt, sums, 0);
        conv_mfma<false><<<dim3(conv_blocks), dim3(256), 0, stream>>>(
            feat, nullptr, nmap, wt, out, sums);
        bn_apply<<<dim3(2048), dim3(256), 0, stream>>>(out, sums, gamma, beta);
    }
}

// Round 4
// 509.698 us; speedup vs baseline: 1.1017x; 1.1017x over previous
//
#include <hip/hip_runtime.h>

#define NVOX 400000
#define K27 27
#define EPS_ 1e-5f

typedef __attribute__((ext_vector_type(8))) short short8;
typedef __attribute__((ext_vector_type(4))) float floatx4;
typedef __attribute__((ext_vector_type(4))) unsigned int uintx4;

// round-to-nearest-even fp32 -> bf16, packed pair (a low 16, b high 16)
__device__ __forceinline__ unsigned int pack2bf(float a, float b) {
    unsigned int ua = __builtin_bit_cast(unsigned int, a);
    unsigned int ub = __builtin_bit_cast(unsigned int, b);
    ua += 0x7fffu + ((ua >> 16) & 1u);
    ub += 0x7fffu + ((ub >> 16) & 1u);
    return (ua >> 16) | (ub & 0xffff0000u);
}

// blocks [0, feat_blocks): fp32->bf16 feature conversion (8 elems/thread)
// blocks [feat_blocks, feat_blocks+2): W[k][ci][co] -> wt[k][co][ci] bf16
// block  [feat_blocks+2]: zero the 128 stats accumulators
__global__ void prep_kernel(const float* __restrict__ w,
                            const float* __restrict__ feat,
                            unsigned short* __restrict__ feat_bf,
                            unsigned short* __restrict__ wt,
                            float* __restrict__ sums,
                            int feat_blocks) {
    const int b = blockIdx.x;
    const int t = threadIdx.x;
    if (b < feat_blocks) {
        const int i0 = b * 2048 + t * 8;
        const floatx4* s = (const floatx4*)(feat + i0);
        const floatx4 f0 = s[0], f1 = s[1];
        uintx4 v;
        v[0] = pack2bf(f0[0], f0[1]); v[1] = pack2bf(f0[2], f0[3]);
        v[2] = pack2bf(f1[0], f1[1]); v[3] = pack2bf(f1[2], f1[3]);
        *(uintx4*)(feat_bf + i0) = v;
    } else if (b < feat_blocks + 2) {
        const int g0 = (b - feat_blocks) * 256 + t;
        for (int g = g0; g < K27 * 64 * 64; g += 512) {
            const int k = g >> 12, r = g & 4095, co = r >> 6, ci = r & 63;
            unsigned int u =
                __builtin_bit_cast(unsigned int, w[(k << 12) + (ci << 6) + co]);
            u += 0x7fffu + ((u >> 16) & 1u);
            wt[g] = (unsigned short)(u >> 16);
        }
    } else {
        if (t < 128) sums[t] = 0.0f;
    }
}

// 128 rows x 64 out-ch per block (3125 blocks exactly). 4 waves, wave tile
// M=32 x N=64 -> acc 2x4 (32 AGPR). Software-pipelined: gather k+1 into
// registers while MFMA-ing k from LDS; vmcnt drains before next iter's
// ds_write, after the MFMAs. LDS uses 16B chunks XOR-swizzled by (row&7):
// writes are 1KB-contiguous per wave-instr, fragment reads 2 lanes/bank.
template <bool BF16FEAT>
__launch_bounds__(256)
__global__ void conv_mfma(const float* __restrict__ feat,
                          const unsigned short* __restrict__ feat_bf,
                          const int* __restrict__ nmap,
                          const unsigned short* __restrict__ wt,
                          float* __restrict__ out,
                          float* __restrict__ sums) {
    __shared__ __align__(16) unsigned short a_tile[128 * 64];  // 16 KB
    __shared__ __align__(16) unsigned short b_tile[64 * 64];   //  8 KB
    __shared__ float cstat[128];

    const int tid  = threadIdx.x;
    const int wv   = tid >> 6;
    const int lane = tid & 63;
    const int m    = lane & 15;
    const int q    = lane >> 4;
    const int base = blockIdx.x * 128;

    // staging descriptors: thread t owns A-chunks c = t+256j (j<4), B-chunks
    // c = t+256j (j<2). chunk = 16B; row = c>>3; swizzled pos = row*8 + ((c&7)^(row&7))
    int arow[4], aoff[4], apos[4];
#pragma unroll
    for (int j = 0; j < 4; ++j) {
        const int c = tid + 256 * j;
        arow[j] = c >> 3;
        aoff[j] = (c & 7) * 8;
        apos[j] = (arow[j] * 8 + ((c & 7) ^ (arow[j] & 7))) * 8;
    }
    int bsrc[2], bpos[2];
#pragma unroll
    for (int j = 0; j < 2; ++j) {
        const int c = tid + 256 * j;
        bsrc[j] = c * 8;
        bpos[j] = ((c >> 3) * 8 + ((c & 7) ^ ((c >> 3) & 7))) * 8;
    }

    floatx4 acc[2][4];
#pragma unroll
    for (int mt = 0; mt < 2; ++mt)
#pragma unroll
        for (int nt = 0; nt < 4; ++nt)
            acc[mt][nt] = (floatx4){0.f, 0.f, 0.f, 0.f};

    short8 areg[4], breg[2];

#define PREFETCH(kk)                                                          \
    do {                                                                      \
        _Pragma("unroll") for (int j = 0; j < 4; ++j) {                       \
            const int idx = nmap[(kk) * NVOX + base + arow[j]];               \
            areg[j] = (short8){0, 0, 0, 0, 0, 0, 0, 0};                       \
            if (idx >= 0) {                                                   \
                if (BF16FEAT) {                                               \
                    areg[j] = *(const short8*)(feat_bf +                      \
                                               (size_t)idx * 64 + aoff[j]);   \
                } else {                                                      \
                    const floatx4* s =                                        \
                        (const floatx4*)(feat + (size_t)idx * 64 + aoff[j]);  \
                    const floatx4 f0 = s[0], f1 = s[1];                       \
                    uintx4 v;                                                 \
                    v[0] = pack2bf(f0[0], f0[1]);                             \
                    v[1] = pack2bf(f0[2], f0[3]);                             \
                    v[2] = pack2bf(f1[0], f1[1]);                             \
                    v[3] = pack2bf(f1[2], f1[3]);                             \
                    areg[j] = __builtin_bit_cast(short8, v);                  \
                }                                                             \
            }                                                                 \
        }                                                                     \
        _Pragma("unroll") for (int j = 0; j < 2; ++j) {                       \
            breg[j] = *(const short8*)(wt + (kk) * 4096 + bsrc[j]);           \
        }                                                                     \
    } while (0)

    PREFETCH(0);

    for (int k = 0; k < K27; ++k) {
        __syncthreads();  // all waves' LDS reads of iter k-1 complete
#pragma unroll
        for (int j = 0; j < 4; ++j) *(short8*)(a_tile + apos[j]) = areg[j];
#pragma unroll
        for (int j = 0; j < 2; ++j) *(short8*)(b_tile + bpos[j]) = breg[j];
        __syncthreads();  // LDS writes visible

        if (k + 1 < K27) PREFETCH(k + 1);  // overlaps with MFMAs below

#pragma unroll
        for (int kb = 0; kb < 2; ++kb) {
            short8 af[2], bf[4];
#pragma unroll
            for (int mt = 0; mt < 2; ++mt) {
                const int row = wv * 32 + mt * 16 + m;
                af[mt] = *(const short8*)(
                    a_tile + (row * 8 + ((kb * 4 + q) ^ (row & 7))) * 8);
            }
#pragma unroll
            for (int nt = 0; nt < 4; ++nt) {
                const int row = nt * 16 + m;
                bf[nt] = *(const short8*)(
                    b_tile + (row * 8 + ((kb * 4 + q) ^ (row & 7))) * 8);
            }
#pragma unroll
            for (int mt = 0; mt < 2; ++mt)
#pragma unroll
                for (int nt = 0; nt < 4; ++nt)
                    acc[mt][nt] = __builtin_amdgcn_mfma_f32_16x16x32_bf16(
                        af[mt], bf[nt], acc[mt][nt], 0, 0, 0);
        }
    }
#undef PREFETCH

    // epilogue: store (C/D: col=lane&15, row=q*4+reg — m89-verified) + stats
    if (tid < 128) cstat[tid] = 0.0f;
    __syncthreads();
#pragma unroll
    for (int nt = 0; nt < 4; ++nt) {
        const int col = nt * 16 + m;
        float s = 0.f, s2 = 0.f;
#pragma unroll
        for (int mt = 0; mt < 2; ++mt) {
            const int row0 = base + wv * 32 + mt * 16 + q * 4;
#pragma unroll
            for (int i = 0; i < 4; ++i) {
                const float v = acc[mt][nt][i];
                s += v;
                s2 += v * v;
                out[(size_t)(row0 + i) * 64 + col] = v;
            }
        }
        atomicAdd(&cstat[col], s);
        atomicAdd(&cstat[64 + col], s2);
    }
    __syncthreads();
    if (tid < 128) atomicAdd(&sums[tid], cstat[tid]);
}

__global__ void bn_apply(float* __restrict__ out, const float* __restrict__ sums,
                         const float* __restrict__ gamma,
                         const float* __restrict__ beta) {
    __shared__ float sc[64];
    __shared__ float sh[64];
    const int tid = threadIdx.x;
    if (tid < 64) {
        const float inv_n = 1.0f / (float)NVOX;
        const float mean = sums[tid] * inv_n;
        const float var  = sums[64 + tid] * inv_n - mean * mean;
        const float g    = gamma[tid] * rsqrtf(var + EPS_);
        sc[tid] = g;
        sh[tid] = beta[tid] - mean * g;
    }
    __syncthreads();
    const int cg = (tid & 15) * 4;
    floatx4 scale, shift;
#pragma unroll
    for (int j = 0; j < 4; ++j) {
        scale[j] = sc[cg + j];
        shift[j] = sh[cg + j];
    }
    floatx4* p = (floatx4*)out;
    const int total4 = NVOX * 16;
    for (int i = blockIdx.x * 256 + tid; i < total4; i += gridDim.x * 256) {
        floatx4 v = p[i] * scale + shift;
#pragma unroll
        for (int j = 0; j < 4; ++j) v[j] = v[j] > 0.f ? v[j] : 0.f;
        p[i] = v;
    }
}

extern "C" void kernel_launch(void* const* d_in, const int* in_sizes, int n_in,
                              void* d_out, int out_size, void* d_ws, size_t ws_size,
                              hipStream_t stream) {
    const float* feat  = (const float*)d_in[0];
    const int*   nmap  = (const int*)d_in[1];
    const float* w     = (const float*)d_in[2];
    const float* gamma = (const float*)d_in[3];
    const float* beta  = (const float*)d_in[4];
    float* out = (float*)d_out;

    const size_t FEATB = (size_t)NVOX * 64 * 2;      // 51,200,000
    const size_t WTB   = (size_t)K27 * 64 * 64 * 2;  //    221,184
    const int conv_blocks = NVOX / 128;              // 3125 exactly

    if (ws_size >= FEATB + WTB + 512) {
        unsigned short* feat_bf = (unsigned short*)d_ws;
        unsigned short* wt      = (unsigned short*)((char*)d_ws + FEATB);
        float* sums             = (float*)((char*)d_ws + FEATB + WTB);
        prep_kernel<<<dim3(12503), dim3(256), 0, stream>>>(
            w, feat, feat_bf, wt, sums, 12500);
        conv_mfma<true><<<dim3(conv_blocks), dim3(256), 0, stream>>>(
            feat, feat_bf, nmap, wt, out, sums);
        bn_apply<<<dim3(2048), dim3(256), 0, stream>>>(out, sums, gamma, beta);
    } else {
        // fallback: fp32 gather + in-register pack (no feature buffer)
        unsigned short* wt = (unsigned short*)d_ws;
        float* sums        = (float*)((char*)d_ws + WTB);
        prep_kernel<<<dim3(3), dim3(256), 0, stream>>>(
            w, feat, nullptr, wt, sums, 0);
        conv_mfma<false><<<dim3(conv_blocks), dim3(256), 0, stream>>>(
            feat, nullptr, nmap, wt, out, sums);
        bn_apply<<<dim3(2048), dim3(256), 0, stream>>>(out, sums, gamma, beta);
    }
}